// Round 4
// baseline (55.976 us; speedup 1.0000x reference)
//
#include <hip/hip_runtime.h>

// LDDMM Hamiltonian evolution, closed-form gradients of
// H = sum_ij exp(-||x_i-x_j||^2/sigma^2) <m_i,m_j>, sigma=0.1:
//   out0 = -dH/dpos = (4/sigma^2) * sum_j K_ij (m_i.m_j)(x_i-x_j)
//   out1 =  dH/dmom = 2 * sum_j K_ij m_j
//
// R3: i-per-thread n-body layout. Each thread owns ONE i (private fp32
// accumulators -> no shuffles, no cross-lane reduction). The j-segment is
// staged ONCE per block in LDS (single barrier) and read at wave-uniform
// addresses (broadcast, conflict-free). j split G ways for occupancy;
// partials in ws[seg][comp][N] (coalesced), deterministic reduce kernel.
// Coordinates pre-scaled by 10*sqrt(log2 e) so K = exp2(-d2) directly.

constexpr int BLOCK = 256;
constexpr double S_D       = 12.011224087864498;     // 10*sqrt(log2(e))
constexpr float  SCALE_POS = (float)S_D;
constexpr float  SCALE_F   = (float)(400.0 / S_D);   // (4/sigma^2)/S_D

struct f2 { float x, y; };

__global__ __launch_bounds__(BLOCK)
void lddmm_main(const float* __restrict__ mom, const float* __restrict__ pos,
                float* __restrict__ ws, int N, int G)
{
    extern __shared__ float4 lds4[];                 // jlen x {sx,sy,sz,mx} ++ jlen/2 x {my,mz}
    const int jlen = N / G;                          // N % G == 0 (N=8192)
    float4* sa = lds4;                               // (x,y,z,mx) scaled pos + mom.x
    f2*     sb = (f2*)(lds4 + jlen);                 // (my,mz)

    const int bid = blockIdx.x;
    const int seg = bid % G;
    const int ib  = bid / G;
    const int tid = threadIdx.x;
    const int i   = ib * BLOCK + tid;
    const int j0  = seg * jlen;

    // ---- stage this block's j-segment into LDS (once) ----
    for (int r = tid; r < jlen; r += BLOCK) {
        const int jg = j0 + r;
        sa[r] = make_float4(SCALE_POS * pos[jg * 3 + 0],
                            SCALE_POS * pos[jg * 3 + 1],
                            SCALE_POS * pos[jg * 3 + 2],
                            mom[jg * 3 + 0]);
        sb[r].x = mom[jg * 3 + 1];
        sb[r].y = mom[jg * 3 + 2];
    }
    __syncthreads();

    // ---- own i data ----
    const int ii = (i < N) ? i : 0;
    const float xi  = SCALE_POS * pos[ii * 3 + 0];
    const float yi  = SCALE_POS * pos[ii * 3 + 1];
    const float zi  = SCALE_POS * pos[ii * 3 + 2];
    const float mxi = mom[ii * 3 + 0];
    const float myi = mom[ii * 3 + 1];
    const float mzi = mom[ii * 3 + 2];

    float fx = 0.f, fy = 0.f, fz = 0.f, gx = 0.f, gy = 0.f, gz = 0.f;

    // ---- main loop: uniform-address LDS reads (broadcast), private accum ----
    #pragma unroll 4
    for (int r = 0; r < jlen; ++r) {
        const float4 a = sa[r];
        const f2     b = sb[r];
        const float dx = xi - a.x;
        const float dy = yi - a.y;
        const float dz = zi - a.z;
        const float d2 = fmaf(dx, dx, fmaf(dy, dy, dz * dz));
        const float e  = exp2f(-d2);                 // = exp(-100*||.||^2) via prescale
        const float md = fmaf(mxi, a.w, fmaf(myi, b.x, mzi * b.y));
        const float w  = e * md;
        fx = fmaf(w, dx, fx);
        fy = fmaf(w, dy, fy);
        fz = fmaf(w, dz, fz);
        gx = fmaf(e, a.w, gx);
        gy = fmaf(e, b.x, gy);
        gz = fmaf(e, b.y, gz);
    }

    if (i < N) {
        float* p = ws + (size_t)seg * 6 * N;         // [seg][comp][N] -> coalesced
        p[0 * N + i] = fx;
        p[1 * N + i] = fy;
        p[2 * N + i] = fz;
        p[3 * N + i] = gx;
        p[4 * N + i] = gy;
        p[5 * N + i] = gz;
    }
}

__global__ __launch_bounds__(BLOCK)
void lddmm_reduce(const float* __restrict__ ws, float* __restrict__ out, int N, int G)
{
    const int i = blockIdx.x * blockDim.x + threadIdx.x;
    if (i >= N) return;
    float s0 = 0.f, s1 = 0.f, s2 = 0.f, s3 = 0.f, s4 = 0.f, s5 = 0.f;
    for (int g = 0; g < G; ++g) {
        const float* p = ws + (size_t)g * 6 * N;
        s0 += p[0 * N + i];
        s1 += p[1 * N + i];
        s2 += p[2 * N + i];
        s3 += p[3 * N + i];
        s4 += p[4 * N + i];
        s5 += p[5 * N + i];
    }
    out[i * 3 + 0] = SCALE_F * s0;
    out[i * 3 + 1] = SCALE_F * s1;
    out[i * 3 + 2] = SCALE_F * s2;
    float* o2 = out + (size_t)N * 3;
    o2[i * 3 + 0] = 2.0f * s3;
    o2[i * 3 + 1] = 2.0f * s4;
    o2[i * 3 + 2] = 2.0f * s5;
}

extern "C" void kernel_launch(void* const* d_in, const int* in_sizes, int n_in,
                              void* d_out, int out_size, void* d_ws, size_t ws_size,
                              hipStream_t stream) {
    const float* mom = (const float*)d_in[0];
    const float* pos = (const float*)d_in[1];
    float* out = (float*)d_out;
    const int N = in_sizes[0] / 3;   // B=1, D=3

    // pick the largest j-split that fits the workspace (all deterministic)
    int G = 32;
    while (G > 1 && (size_t)G * 6 * N * sizeof(float) > ws_size) G >>= 1;

    const int jlen = N / G;
    const size_t shmem = (size_t)jlen * 16 + (size_t)jlen * 8;  // sa + sb

    const int nib = (N + BLOCK - 1) / BLOCK;
    lddmm_main<<<dim3(nib * G), dim3(BLOCK), shmem, stream>>>(mom, pos, (float*)d_ws, N, G);
    lddmm_reduce<<<dim3((N + BLOCK - 1) / BLOCK), dim3(BLOCK), 0, stream>>>((const float*)d_ws, out, N, G);
}